// Round 6
// baseline (181.898 us; speedup 1.0000x reference)
//
#include <hip/hip_runtime.h>

static constexpr int NND = 100000;        // nodes
static constexpr int NED = 3200000;       // edges (before self-loops)
static constexpr int NB  = (NND + 255) / 256;   // 391 buckets of 256 nodes
static constexpr int NCHUNK = 256;              // edge chunks
static constexpr int EPC = NED / NCHUNK;        // 12500 edges per chunk
static constexpr int SCAN_N = NB * NCHUNK;      // 100096

// ---------------- partition pass 1: per-(chunk,bucket) histogram ----------------

__global__ void k_hist(const int* __restrict__ dst, int* __restrict__ counts) {
    __shared__ int h[NB];
    for (int i = threadIdx.x; i < NB; i += 256) h[i] = 0;
    __syncthreads();
    int c = blockIdx.x;
    int base = c * EPC;
    for (int i = threadIdx.x; i < EPC; i += 256)
        atomicAdd(&h[dst[base + i] >> 8], 1);
    __syncthreads();
    for (int b = threadIdx.x; b < NB; b += 256)
        counts[b * NCHUNK + c] = h[b];   // bucket-major for the scan
}

// ---------------- scan (exclusive), 1024 elems/block ----------------

__global__ void k_scan1(const int* __restrict__ in, int* __restrict__ excl,
                        int* __restrict__ blockSums, int n) {
    __shared__ int lds[256];
    int tid = threadIdx.x;
    int base = blockIdx.x * 1024 + tid * 4;
    int v[4]; int sum = 0;
#pragma unroll
    for (int k = 0; k < 4; ++k) { int idx = base + k; v[k] = (idx < n) ? in[idx] : 0; sum += v[k]; }
    lds[tid] = sum; __syncthreads();
    for (int off = 1; off < 256; off <<= 1) {
        int x = lds[tid];
        int y = (tid >= off) ? lds[tid - off] : 0;
        __syncthreads();
        lds[tid] = x + y;
        __syncthreads();
    }
    int run = lds[tid] - sum;
#pragma unroll
    for (int k = 0; k < 4; ++k) { int idx = base + k; if (idx < n) excl[idx] = run; run += v[k]; }
    if (tid == 0) blockSums[blockIdx.x] = lds[255];
}

__global__ void k_scan2(int* __restrict__ blockSums, int nb) {  // single block, 128 thr
    __shared__ int lds[128];
    int tid = threadIdx.x;
    int v = (tid < nb) ? blockSums[tid] : 0;
    lds[tid] = v; __syncthreads();
    for (int off = 1; off < 128; off <<= 1) {
        int x = lds[tid];
        int y = (tid >= off) ? lds[tid - off] : 0;
        __syncthreads();
        lds[tid] = x + y;
        __syncthreads();
    }
    if (tid < nb) blockSums[tid] = lds[tid] - v;
}

__global__ void k_scan3(int* __restrict__ excl, const int* __restrict__ blockSums,
                        int n, int e) {
    int i = blockIdx.x * blockDim.x + threadIdx.x;
    if (i < n) excl[i] += blockSums[i >> 10];
    if (i == n) excl[n] = e;
}

// ---------------- partition pass 2: scatter into bucket runs ----------------
// pack = src | (dst&255)<<20   (src < 2^20)

__global__ void k_part(const int* __restrict__ src, const int* __restrict__ dst,
                       const int* __restrict__ excl, int* __restrict__ tmp) {
    __shared__ int cur[NB];
    int c = blockIdx.x;
    for (int b = threadIdx.x; b < NB; b += 256) cur[b] = excl[b * NCHUNK + c];
    __syncthreads();
    int base = c * EPC;
    for (int i = threadIdx.x; i < EPC; i += 256) {
        int d = dst[base + i];
        int s = src[base + i];
        int b = d >> 8;
        int pos = atomicAdd(&cur[b], 1);
        tmp[pos] = s | ((d & 255) << 20);
    }
}

// ------- per-bucket: deg/dinv/rowptr + CSR fill + fused layer-1 prep -------

__global__ void k_bucket(const int* __restrict__ excl, const int* __restrict__ tmp,
                         int* __restrict__ ssrc, int* __restrict__ rowptr,
                         float* __restrict__ dinv, const float* __restrict__ x,
                         float4* __restrict__ t4) {
    __shared__ int cnt[256];
    __shared__ int lds[256];
    int b = blockIdx.x, t = threadIdx.x;
    int start = excl[b * NCHUNK];
    int end   = excl[(b + 1) * NCHUNK];
    cnt[t] = 0;
    __syncthreads();
    for (int i = start + t; i < end; i += 256)
        atomicAdd(&cnt[tmp[i] >> 20], 1);
    __syncthreads();
    int v = cnt[t];
    lds[t] = v; __syncthreads();
    for (int off = 1; off < 256; off <<= 1) {
        int xv = lds[t];
        int y = (t >= off) ? lds[t - off] : 0;
        __syncthreads();
        lds[t] = xv + y;
        __syncthreads();
    }
    int node = b * 256 + t;
    int rp = start + lds[t] - v;
    if (node < NND) {
        rowptr[node] = rp;
        float d = rsqrtf((float)(v + 1));  // +1 self-loop
        dinv[node] = d;
        const float* xr = x + (size_t)node * 3;   // fused prep1
        t4[node] = make_float4(xr[0] * d, xr[1] * d, xr[2] * d, 0.f);
    }
    if (b == 0 && t == 0) rowptr[NND] = NED;
    cnt[t] = rp;
    __syncthreads();
    for (int i = start + t; i < end; i += 256) {
        int p = tmp[i];
        int pos = atomicAdd(&cnt[p >> 20], 1);
        ssrc[pos] = p & 0xFFFFF;
    }
}

// ------- layer1: gather 4-wide + fused 3->16 matmul -> split tables -------
// t16a[n][8] = feats 0..7,  t16b[n][8] = feats 8..15 of relu((dinv*agg)@W1+b1)*dinv

__global__ void k_g4mm1(const int* __restrict__ rowptr, const int* __restrict__ ssrc,
                        const float4* __restrict__ t4, const float* __restrict__ dinv,
                        const float* __restrict__ W1, const float* __restrict__ b1,
                        float* __restrict__ t16a, float* __restrict__ t16b, int n) {
    __shared__ float sW[48];
    __shared__ float sb[16];
    if (threadIdx.x < 48) sW[threadIdx.x] = W1[threadIdx.x];
    if (threadIdx.x < 16) sb[threadIdx.x] = b1[threadIdx.x];
    __syncthreads();
    int node = blockIdx.x * blockDim.x + threadIdx.x;
    if (node >= n) return;

    float4 a = t4[node];
    float a0 = a.x, a1 = a.y, a2 = a.z;
    int beg = rowptr[node], end = rowptr[node + 1];
    constexpr int U = 8;
    int j = beg;
    for (; j + U <= end; j += U) {
        int s[U];
#pragma unroll
        for (int k = 0; k < U; ++k) s[k] = ssrc[j + k];
        float4 v[U];
#pragma unroll
        for (int k = 0; k < U; ++k) v[k] = t4[s[k]];
#pragma unroll
        for (int k = 0; k < U; ++k) { a0 += v[k].x; a1 += v[k].y; a2 += v[k].z; }
    }
    for (; j < end; ++j) {
        float4 v = t4[ssrc[j]];
        a0 += v.x; a1 += v.y; a2 += v.z;
    }
    float d = dinv[node];
    float p0 = a0 * d, p1 = a1 * d, p2 = a2 * d;
    float h[16];
#pragma unroll
    for (int jj = 0; jj < 16; ++jj) {
        float hv = fmaf(p0, sW[jj], fmaf(p1, sW[16 + jj], fmaf(p2, sW[32 + jj], sb[jj])));
        h[jj] = fmaxf(hv, 0.f) * d;
    }
    float* ra = t16a + (size_t)node * 8;
    float* rb = t16b + (size_t)node * 8;
    *reinterpret_cast<float4*>(ra)     = make_float4(h[0], h[1], h[2], h[3]);
    *reinterpret_cast<float4*>(ra + 4) = make_float4(h[4], h[5], h[6], h[7]);
    *reinterpret_cast<float4*>(rb)     = make_float4(h[8], h[9], h[10], h[11]);
    *reinterpret_cast<float4*>(rb + 4) = make_float4(h[12], h[13], h[14], h[15]);
}

// ------- layer2 pass A: u8a[n][8] = dinv*(tab[n] + sum tab[src]), tab = t16a -------

__global__ void k_g8(const int* __restrict__ rowptr, const int* __restrict__ ssrc,
                     const float* __restrict__ tab, const float* __restrict__ dinv,
                     float* __restrict__ u, int n) {
    constexpr int U = 8;
    int i = blockIdx.x * blockDim.x + threadIdx.x;
    int node = i >> 1;
    int f0 = (i & 1) * 4;
    if (node >= n) return;
    float4 acc = *reinterpret_cast<const float4*>(tab + (size_t)node * 8 + f0);
    int beg = rowptr[node], end = rowptr[node + 1];
    int j = beg;
    for (; j + U <= end; j += U) {
        int s[U];
#pragma unroll
        for (int k = 0; k < U; ++k) s[k] = ssrc[j + k];
        float4 v[U];
#pragma unroll
        for (int k = 0; k < U; ++k)
            v[k] = *reinterpret_cast<const float4*>(tab + (size_t)s[k] * 8 + f0);
#pragma unroll
        for (int k = 0; k < U; ++k) {
            acc.x += v[k].x; acc.y += v[k].y; acc.z += v[k].z; acc.w += v[k].w;
        }
    }
    for (; j < end; ++j) {
        float4 v = *reinterpret_cast<const float4*>(tab + (size_t)ssrc[j] * 8 + f0);
        acc.x += v.x; acc.y += v.y; acc.z += v.z; acc.w += v.w;
    }
    float d = dinv[node];
    acc.x *= d; acc.y *= d; acc.z *= d; acc.w *= d;
    *reinterpret_cast<float4*>(u + (size_t)node * 8 + f0) = acc;
}

// ------- layer2 pass B + fused W2/relu/W3: t3 = (relu(u16@W2+b2)@W3)*dinv -------
// lane pair (i, i^1) owns one node; each lane gathers 4 feats of t16b.

__global__ void k_g8mm(const int* __restrict__ rowptr, const int* __restrict__ ssrc,
                       const float* __restrict__ tabB, const float* __restrict__ u8a,
                       const float* __restrict__ dinv,
                       const float* __restrict__ W2, const float* __restrict__ b2,
                       const float* __restrict__ W3, float2* __restrict__ t3, int n) {
    __shared__ float sW2[512];
    __shared__ float sb2[32];
    __shared__ float sW3[64];
    for (int i = threadIdx.x; i < 512; i += 256) sW2[i] = W2[i];
    if (threadIdx.x < 32) sb2[threadIdx.x] = b2[threadIdx.x];
    if (threadIdx.x < 64) sW3[threadIdx.x] = W3[threadIdx.x];
    __syncthreads();

    constexpr int U = 8;
    int i = blockIdx.x * blockDim.x + threadIdx.x;
    int node = i >> 1;
    int half = i & 1;
    int f0 = half * 4;
    if (node >= n) return;

    float4 acc = *reinterpret_cast<const float4*>(tabB + (size_t)node * 8 + f0);
    int beg = rowptr[node], end = rowptr[node + 1];
    int j = beg;
    for (; j + U <= end; j += U) {
        int s[U];
#pragma unroll
        for (int k = 0; k < U; ++k) s[k] = ssrc[j + k];
        float4 v[U];
#pragma unroll
        for (int k = 0; k < U; ++k)
            v[k] = *reinterpret_cast<const float4*>(tabB + (size_t)s[k] * 8 + f0);
#pragma unroll
        for (int k = 0; k < U; ++k) {
            acc.x += v[k].x; acc.y += v[k].y; acc.z += v[k].z; acc.w += v[k].w;
        }
    }
    for (; j < end; ++j) {
        float4 v = *reinterpret_cast<const float4*>(tabB + (size_t)ssrc[j] * 8 + f0);
        acc.x += v.x; acc.y += v.y; acc.z += v.z; acc.w += v.w;
    }
    float d = dinv[node];
    // this lane's upper-half quad: u[8+f0 .. 8+f0+3]
    float up[4] = {acc.x * d, acc.y * d, acc.z * d, acc.w * d};
    // this lane's lower-half quad from pass A: u[f0 .. f0+3]
    float4 lo4 = *reinterpret_cast<const float4*>(u8a + (size_t)node * 8 + f0);
    float lo[4] = {lo4.x, lo4.y, lo4.z, lo4.w};
    // partner exchange (lane^1 same node)
    float plo[4], pup[4];
#pragma unroll
    for (int c = 0; c < 4; ++c) {
        plo[c] = __shfl_xor(lo[c], 1);
        pup[c] = __shfl_xor(up[c], 1);
    }
    // assemble u[16] with compile-time indices (runtime selects only)
    float uu[16];
#pragma unroll
    for (int c = 0; c < 4; ++c) {
        uu[c]      = half ? plo[c] : lo[c];   // u[0..3]
        uu[4 + c]  = half ? lo[c]  : plo[c];  // u[4..7]
        uu[8 + c]  = half ? pup[c] : up[c];   // u[8..11]
        uu[12 + c] = half ? up[c]  : pup[c];  // u[12..15]
    }
    // this lane computes columns jj = half*16 .. half*16+15
    float t30 = 0.f, t31 = 0.f;
    int jbase = half * 16;
#pragma unroll
    for (int r = 0; r < 16; ++r) {
        int jj = jbase + r;
        float h = sb2[jj];
#pragma unroll
        for (int k = 0; k < 16; ++k) h = fmaf(uu[k], sW2[k * 32 + jj], h);
        h = fmaxf(h, 0.f);
        t30 = fmaf(h, sW3[jj * 2 + 0], t30);
        t31 = fmaf(h, sW3[jj * 2 + 1], t31);
    }
    t30 += __shfl_xor(t30, 1);
    t31 += __shfl_xor(t31, 1);
    if (half == 0) t3[node] = make_float2(t30 * d, t31 * d);
}

// ---------------- layer3: gather 2-wide + bias ----------------

__global__ void k_g2(const int* __restrict__ rowptr, const int* __restrict__ ssrc,
                     const float2* __restrict__ t3, const float* __restrict__ dinv,
                     const float* __restrict__ b3, float2* __restrict__ out, int n) {
    constexpr int U = 8;
    int node = blockIdx.x * blockDim.x + threadIdx.x;
    if (node >= n) return;
    float2 t = t3[node];
    float a0 = t.x, a1 = t.y;
    int beg = rowptr[node], end = rowptr[node + 1];
    int j = beg;
    for (; j + U <= end; j += U) {
        int s[U];
#pragma unroll
        for (int k = 0; k < U; ++k) s[k] = ssrc[j + k];
        float2 v[U];
#pragma unroll
        for (int k = 0; k < U; ++k) v[k] = t3[s[k]];
#pragma unroll
        for (int k = 0; k < U; ++k) { a0 += v[k].x; a1 += v[k].y; }
    }
    for (; j < end; ++j) {
        float2 v = t3[ssrc[j]];
        a0 += v.x; a1 += v.y;
    }
    float d = dinv[node];
    out[node] = make_float2(fmaf(d, a0, b3[0]), fmaf(d, a1, b3[1]));
}

// ---------------- launch ----------------

static inline size_t align256(size_t x) { return (x + 255) & ~(size_t)255; }

extern "C" void kernel_launch(void* const* d_in, const int* in_sizes, int n_in,
                              void* d_out, int out_size, void* d_ws, size_t ws_size,
                              hipStream_t stream) {
    const float* x  = (const float*)d_in[0];
    const int*   ei = (const int*)d_in[1];
    const float* W1 = (const float*)d_in[2];
    const float* b1 = (const float*)d_in[3];
    const float* W2 = (const float*)d_in[4];
    const float* b2 = (const float*)d_in[5];
    const float* W3 = (const float*)d_in[6];
    const float* b3 = (const float*)d_in[7];
    float2* out = (float2*)d_out;

    const int* src = ei;
    const int* dst = ei + NED;

    char* p = (char*)d_ws;
    float* dinv   = (float*)p; p += align256(sizeof(float) * (size_t)NND);
    int*   rowptr = (int*)p;   p += align256(sizeof(int) * (size_t)(NND + 1));
    int*   excl   = (int*)p;   p += align256(sizeof(int) * (size_t)(SCAN_N + 1));
    int*   bsums  = (int*)p;   p += align256(sizeof(int) * 128);
    int*   ssrc   = (int*)p;   p += align256(sizeof(int) * (size_t)NED);
    float4* t4    = (float4*)p; p += align256(sizeof(float4) * (size_t)NND);
    float2* t3    = (float2*)p; p += align256(sizeof(float2) * (size_t)NND);
    // region shared by tmp (dead after k_bucket) and the layer-2 tables
    char*  q      = p;         p += align256(sizeof(int) * (size_t)NED);
    int*   tmp    = (int*)q;
    float* t16a   = (float*)q;                                   // [NND][8]
    float* t16b   = t16a + (size_t)NND * 8;                      // [NND][8]
    float* u8a    = t16b + (size_t)NND * 8;                      // [NND][8]

    const int B = 256;
    const int gridN = (NND + B - 1) / B;
    const int grid2N = (NND * 2 + B - 1) / B;
    const int nScanBlocks = (SCAN_N + 1023) / 1024;  // 98

    // ---- CSR build (+ fused layer-1 prep in k_bucket) ----
    k_hist<<<NCHUNK, B, 0, stream>>>(dst, excl);
    k_scan1<<<nScanBlocks, 256, 0, stream>>>(excl, excl, bsums, SCAN_N);
    k_scan2<<<1, 128, 0, stream>>>(bsums, nScanBlocks);
    k_scan3<<<(SCAN_N + 1 + B - 1) / B, B, 0, stream>>>(excl, bsums, SCAN_N, NED);
    k_part<<<NCHUNK, B, 0, stream>>>(src, dst, excl, tmp);
    k_bucket<<<NB, B, 0, stream>>>(excl, tmp, ssrc, rowptr, dinv, x, t4);

    // ---- layer 1: aggregate 4-wide, fused 3->16, split-table output ----
    k_g4mm1<<<gridN, B, 0, stream>>>(rowptr, ssrc, t4, dinv, W1, b1, t16a, t16b, NND);

    // ---- layer 2: two 8-wide gathers; pass B fuses W2+relu+W3 ----
    k_g8<<<grid2N, B, 0, stream>>>(rowptr, ssrc, t16a, dinv, u8a, NND);
    k_g8mm<<<grid2N, B, 0, stream>>>(rowptr, ssrc, t16b, u8a, dinv, W2, b2, W3, t3, NND);

    // ---- layer 3: gather 2-wide ----
    k_g2<<<gridN, B, 0, stream>>>(rowptr, ssrc, t3, dinv, b3, out, NND);
}